// Round 9
// baseline (8230.434 us; speedup 1.0000x reference)
//
#include <hip/hip_runtime.h>
#include <hip/hip_bf16.h>
#include <math.h>

#define T_STEPS 512
#define BATCH   128
#define ISZ     256
#define HSZ     256
#define G4      1024   // 4*H
#define KSL     16     // k4 slices per quad member (64/4)
#define QWIN    8      // gates_x window (quad kernel)

// ---------------------------------------------------------------------------
// prep: transposed weight tables WT4[k4][row][c] = W[row][4*k4+c], so a wave
// reading lane-consecutive rows at fixed k4 issues coalesced float4 loads.
// ---------------------------------------------------------------------------
__global__ __launch_bounds__(256) void prep_tables(
    const float* __restrict__ W_hh, const float* __restrict__ W_ih,
    float* __restrict__ WT4h, float* __restrict__ WT4i) {
  int idx = blockIdx.x * 256 + threadIdx.x;   // 0 .. 262143
  int k4 = idx >> 12;          // 0..63
  int r  = (idx >> 2) & 1023;  // row
  int c  = idx & 3;
  WT4h[idx] = W_hh[r * 256 + k4 * 4 + c];
  WT4i[idx] = W_ih[r * 256 + k4 * 4 + c];
}

// ---------------------------------------------------------------------------
// QUAD kernel: 256 WGs = 64 quads x 4 members. Quad q serves batch rows
// {2q, 2q+1}; member m streams only k4 in [m*16, m*16+16) of W_hh/W_ih
// (256 KB/step vs 1 MB) -> attacks the measured ~100 GB/s/CU L2 wall.
// Per step: each member computes partial gates (both rows, its k-quarter),
// writes 8 KB partials to L2 scratch, release-flag (step-tagged), acquire-
// polls the 3 partners, sums ALL FOUR partial sets in fixed order (bit-
// identical across members -> replicated h/c, no h exchange), updates h/c.
// Member 0 writes ys/h_T/c_T. gates_x fused in QWIN-step windows.
// ---------------------------------------------------------------------------
__global__ __launch_bounds__(512, 2) void lstm_quad(
    const float* __restrict__ x,     // [T][B][256]
    const float* __restrict__ WT4h,  // [64][1024][4]
    const float* __restrict__ WT4i,  // [64][1024][4]
    const float* __restrict__ bih, const float* __restrict__ bhh,
    const float* __restrict__ h0, const float* __restrict__ c0,
    float* __restrict__ out,
    unsigned int* __restrict__ flags,  // [64][4][2] stride-16 uints, memset 0
    float* __restrict__ part) {        // [64][4][2][2][1024] fp32
  __shared__ __align__(16) float x_lds[2][QWIN][68];   // 4.35 KB (local k)
  __shared__ __align__(16) float gx_lds[2][QWIN][G4];  // 64 KB
  __shared__ __align__(16) float h_lds[2][HSZ];        // 2 KB
  __shared__ __align__(16) float g_lds[2][G4];         // 8 KB

  const int wg = blockIdx.x;
  const int m  = wg >> 6;          // member 0..3 (blocks q,q+64,... same XCD)
  const int q  = wg & 63;          // quad id
  const int b0 = q * 2;
  const int t  = threadIdx.x;      // 0..511
  const int r  = t;                // gate rows r, r+512
  const int rg = t >> 2;           // gemm: gate-row group (8 rows)
  const int sg = t & 3;            // gemm: step-pair group (2 steps)
  const int k4lo = m * KSL;        // this member's k4 range
  const int klo  = k4lo * 4;       // float offset in k
  const int ur = t >> 8;           // update: batch row (0/1)
  const int uc = t & 255;          // update: h column

  // bias added by member 0 only (so the 4-way sum has it exactly once)
  float bias_g[8];
  #pragma unroll
  for (int i = 0; i < 8; ++i)
    bias_g[i] = (m == 0) ? (bih[rg * 8 + i] + bhh[rg * 8 + i]) : 0.f;

  h_lds[ur][uc] = h0[(b0 + ur) * HSZ + uc];
  float c = c0[(b0 + ur) * HSZ + uc];
  __syncthreads();

  for (int w = 0; w < T_STEPS / QWIN; ++w) {
    const int s0 = w * QWIN;

    // ---- stage x window (this member's k-quarter): 2 rows x 8 steps x 16 f4
    if (t < 256) {
      int brow = t >> 7, s = (t >> 4) & 7, f4 = t & 15;
      float4 v = *reinterpret_cast<const float4*>(
          &x[((size_t)(s0 + s) * BATCH + b0 + brow) * ISZ + klo + f4 * 4]);
      *reinterpret_cast<float4*>(&x_lds[brow][s][f4 * 4]) = v;
    }
    __syncthreads();

    // ---- windowed gates_x partial GEMM: acc[8 gaterows][2 steps][2 rows]
    float acc[8][2][2];
    #pragma unroll
    for (int i = 0; i < 8; ++i)
      #pragma unroll
      for (int s2 = 0; s2 < 2; ++s2)
        #pragma unroll
        for (int br = 0; br < 2; ++br) acc[i][s2][br] = bias_g[i];

    #pragma unroll 4
    for (int k4 = 0; k4 < KSL; ++k4) {
      float4 xv[2][2];
      #pragma unroll
      for (int s2 = 0; s2 < 2; ++s2)
        #pragma unroll
        for (int br = 0; br < 2; ++br)
          xv[s2][br] = *reinterpret_cast<const float4*>(&x_lds[br][sg * 2 + s2][k4 * 4]);
      #pragma unroll
      for (int i = 0; i < 8; ++i) {
        float4 wv = *reinterpret_cast<const float4*>(
            &WT4i[(size_t)(k4lo + k4) * 4096 + (rg * 8 + i) * 4]);
        #pragma unroll
        for (int s2 = 0; s2 < 2; ++s2)
          #pragma unroll
          for (int br = 0; br < 2; ++br)
            acc[i][s2][br] += wv.x * xv[s2][br].x + wv.y * xv[s2][br].y +
                              wv.z * xv[s2][br].z + wv.w * xv[s2][br].w;
      }
    }
    #pragma unroll
    for (int i = 0; i < 8; ++i)
      #pragma unroll
      for (int s2 = 0; s2 < 2; ++s2)
        #pragma unroll
        for (int br = 0; br < 2; ++br)
          gx_lds[br][sg * 2 + s2][rg * 8 + i] = acc[i][s2][br];
    __syncthreads();

    // ---- QWIN recurrent steps ----
    for (int s = 0; s < QWIN; ++s) {
      const int step = s0 + s;
      const int par  = step & 1;

      float a00 = gx_lds[0][s][r], a01 = gx_lds[0][s][r + 512];
      float a10 = gx_lds[1][s][r], a11 = gx_lds[1][s][r + 512];

      // partial recurrent dot over this member's k-quarter, both batch rows
      #pragma unroll 8
      for (int k4 = k4lo; k4 < k4lo + KSL; ++k4) {
        float4 w0 = *reinterpret_cast<const float4*>(&WT4h[(size_t)k4 * 4096 + r * 4]);
        float4 w1 = *reinterpret_cast<const float4*>(&WT4h[(size_t)k4 * 4096 + (r + 512) * 4]);
        float4 ha = *reinterpret_cast<const float4*>(&h_lds[0][k4 * 4]);
        float4 hb = *reinterpret_cast<const float4*>(&h_lds[1][k4 * 4]);
        a00 += w0.x * ha.x + w0.y * ha.y + w0.z * ha.z + w0.w * ha.w;
        a01 += w1.x * ha.x + w1.y * ha.y + w1.z * ha.z + w1.w * ha.w;
        a10 += w0.x * hb.x + w0.y * hb.y + w0.z * hb.z + w0.w * hb.w;
        a11 += w1.x * hb.x + w1.y * hb.y + w1.z * hb.z + w1.w * hb.w;
      }

      // publish partials (agent scope; bypasses L1)
      float* pb = part + ((size_t)(q * 4 + m) * 2 + par) * 2048;
      __hip_atomic_store(&pb[r],          a00, __ATOMIC_RELAXED, __HIP_MEMORY_SCOPE_AGENT);
      __hip_atomic_store(&pb[r + 512],    a01, __ATOMIC_RELAXED, __HIP_MEMORY_SCOPE_AGENT);
      __hip_atomic_store(&pb[1024 + r],   a10, __ATOMIC_RELAXED, __HIP_MEMORY_SCOPE_AGENT);
      __hip_atomic_store(&pb[1024 + r + 512], a11, __ATOMIC_RELAXED, __HIP_MEMORY_SCOPE_AGENT);
      __syncthreads();
      if (t == 0) {
        __threadfence();
        __hip_atomic_store(&flags[((q * 4 + m) * 2 + par) * 16], (unsigned)(step + 1),
                           __ATOMIC_RELEASE, __HIP_MEMORY_SCOPE_AGENT);
      }
      if (t < 4) {  // thread j polls member j's flag (step-tagged, monotonic)
        unsigned int* f = &flags[((q * 4 + t) * 2 + par) * 16];
        int guard = 0;
        while (__hip_atomic_load(f, __ATOMIC_ACQUIRE, __HIP_MEMORY_SCOPE_AGENT) <
               (unsigned)(step + 1)) {
          __builtin_amdgcn_s_sleep(1);
          if (++guard > (1 << 26)) break;  // bailout: never wedge the GPU
        }
      }
      __syncthreads();

      // sum all 4 members' partials in FIXED order -> bit-identical everywhere
      float g00 = 0.f, g01 = 0.f, g10 = 0.f, g11 = 0.f;
      #pragma unroll
      for (int mm = 0; mm < 4; ++mm) {
        float* pm = part + ((size_t)(q * 4 + mm) * 2 + par) * 2048;
        g00 += __hip_atomic_load(&pm[r],            __ATOMIC_RELAXED, __HIP_MEMORY_SCOPE_AGENT);
        g01 += __hip_atomic_load(&pm[r + 512],      __ATOMIC_RELAXED, __HIP_MEMORY_SCOPE_AGENT);
        g10 += __hip_atomic_load(&pm[1024 + r],     __ATOMIC_RELAXED, __HIP_MEMORY_SCOPE_AGENT);
        g11 += __hip_atomic_load(&pm[1024 + r + 512], __ATOMIC_RELAXED, __HIP_MEMORY_SCOPE_AGENT);
      }
      g_lds[0][r] = g00; g_lds[0][r + 512] = g01;
      g_lds[1][r] = g10; g_lds[1][r + 512] = g11;
      __syncthreads();

      // gate nonlinearities + state update (i,f,g,o) — replicated, identical
      {
        float gi = g_lds[ur][uc];
        float gf = g_lds[ur][uc + 256];
        float gg = g_lds[ur][uc + 512];
        float go = g_lds[ur][uc + 768];
        gi = 1.f / (1.f + expf(-gi));
        gf = 1.f / (1.f + expf(-gf));
        go = 1.f / (1.f + expf(-go));
        gg = tanhf(gg);
        c = gf * c + gi * gg;
        float h = go * tanhf(c);
        h_lds[ur][uc] = h;
        if (m == 0)
          out[(size_t)step * BATCH * HSZ + (b0 + ur) * HSZ + uc] = h;
      }
      __syncthreads();
    }
  }

  if (m == 0) {
    out[(size_t)T_STEPS * BATCH * HSZ + (b0 + ur) * HSZ + uc] = h_lds[ur][uc];
    out[(size_t)T_STEPS * BATCH * HSZ + (size_t)BATCH * HSZ + (b0 + ur) * HSZ + uc] = c;
  }
}

// ---------------------------------------------------------------------------
// Fallback (R7, measured 5.68 ms): 128 WGs, full-k per WG, windowed gates_x.
// ---------------------------------------------------------------------------
#define WIN  16
#define XPAD 4
__global__ __launch_bounds__(512, 2) void lstm_fused(
    const float* __restrict__ x, const float* __restrict__ WT4h,
    const float* __restrict__ WT4i, const float* __restrict__ bih,
    const float* __restrict__ bhh, const float* __restrict__ h0,
    const float* __restrict__ c0, float* __restrict__ out) {
  __shared__ __align__(16) float x_lds[WIN][HSZ + XPAD];
  __shared__ __align__(16) float gx_lds[WIN][G4];
  __shared__ __align__(16) float h_lds[HSZ];
  __shared__ __align__(16) float g_lds[G4];
  const int b = blockIdx.x;
  const int t = threadIdx.x;
  const int r = t;
  const int rg = t >> 2;
  const int sg = t & 3;
  float bias_g[8];
  #pragma unroll
  for (int i = 0; i < 8; ++i) bias_g[i] = bih[rg * 8 + i] + bhh[rg * 8 + i];
  if (t < HSZ) h_lds[t] = h0[b * HSZ + t];
  float c = (t < HSZ) ? c0[b * HSZ + t] : 0.f;
  __syncthreads();
  for (int w = 0; w < T_STEPS / WIN; ++w) {
    const int s0 = w * WIN;
    #pragma unroll
    for (int j = 0; j < 2; ++j) {
      int f = t + j * 512;
      int s = f >> 6, kq = f & 63;
      float4 v = reinterpret_cast<const float4*>(x)[((size_t)(s0 + s) * BATCH + b) * 64 + kq];
      *reinterpret_cast<float4*>(&x_lds[s][kq * 4]) = v;
    }
    __syncthreads();
    float acc[8][4];
    #pragma unroll
    for (int i = 0; i < 8; ++i)
      #pragma unroll
      for (int ss = 0; ss < 4; ++ss) acc[i][ss] = bias_g[i];
    #pragma unroll 4
    for (int k4 = 0; k4 < 64; ++k4) {
      float4 xv[4];
      #pragma unroll
      for (int ss = 0; ss < 4; ++ss)
        xv[ss] = *reinterpret_cast<const float4*>(&x_lds[sg * 4 + ss][k4 * 4]);
      #pragma unroll
      for (int i = 0; i < 8; ++i) {
        float4 wv = *reinterpret_cast<const float4*>(&WT4i[(size_t)k4 * 4096 + (rg * 8 + i) * 4]);
        #pragma unroll
        for (int ss = 0; ss < 4; ++ss)
          acc[i][ss] += wv.x * xv[ss].x + wv.y * xv[ss].y + wv.z * xv[ss].z + wv.w * xv[ss].w;
      }
    }
    #pragma unroll
    for (int i = 0; i < 8; ++i)
      #pragma unroll
      for (int ss = 0; ss < 4; ++ss)
        gx_lds[sg * 4 + ss][rg * 8 + i] = acc[i][ss];
    __syncthreads();
    for (int s = 0; s < WIN; ++s) {
      float a0 = gx_lds[s][r];
      float a1 = gx_lds[s][r + 512];
      float sa0 = 0.f, sa1 = 0.f;
      #pragma unroll 8
      for (int k4 = 0; k4 < 64; ++k4) {
        float4 w0 = *reinterpret_cast<const float4*>(&WT4h[(size_t)k4 * 4096 + r * 4]);
        float4 w1 = *reinterpret_cast<const float4*>(&WT4h[(size_t)k4 * 4096 + (r + 512) * 4]);
        float4 hv = *reinterpret_cast<const float4*>(&h_lds[k4 * 4]);
        sa0 += w0.x * hv.x + w0.y * hv.y + w0.z * hv.z + w0.w * hv.w;
        sa1 += w1.x * hv.x + w1.y * hv.y + w1.z * hv.z + w1.w * hv.w;
      }
      a0 += sa0; a1 += sa1;
      g_lds[r] = a0;
      g_lds[r + 512] = a1;
      __syncthreads();
      if (t < HSZ) {
        float gi = g_lds[t], gf = g_lds[t + 256], gg = g_lds[t + 512], go = g_lds[t + 768];
        gi = 1.f / (1.f + expf(-gi));
        gf = 1.f / (1.f + expf(-gf));
        go = 1.f / (1.f + expf(-go));
        gg = tanhf(gg);
        c = gf * c + gi * gg;
        float h = go * tanhf(c);
        h_lds[t] = h;
        out[(size_t)(s0 + s) * BATCH * HSZ + b * HSZ + t] = h;
      }
      __syncthreads();
    }
  }
  if (t < HSZ) {
    out[(size_t)T_STEPS * BATCH * HSZ + b * HSZ + t] = h_lds[t];
    out[(size_t)T_STEPS * BATCH * HSZ + (size_t)BATCH * HSZ + b * HSZ + t] = c;
  }
}

// ---------------------------------------------------------------------------
extern "C" void kernel_launch(void* const* d_in, const int* in_sizes, int n_in,
                              void* d_out, int out_size, void* d_ws, size_t ws_size,
                              hipStream_t stream) {
  const float* x   = (const float*)d_in[0];
  const float* h0  = (const float*)d_in[1];
  const float* c0  = (const float*)d_in[2];
  const float* Wih = (const float*)d_in[3];
  const float* Whh = (const float*)d_in[4];
  const float* bih = (const float*)d_in[5];
  const float* bhh = (const float*)d_in[6];
  float* out = (float*)d_out;

  char* ws = (char*)d_ws;
  float* WT4h = (float*)ws;                              // 1 MB
  float* WT4i = (float*)(ws + (1 << 20));                // 1 MB
  unsigned int* flags = (unsigned int*)(ws + (2 << 20)); // 32 KB
  float* part = (float*)(ws + (2 << 20) + (64 << 10));   // 4 MB

  const size_t NEED_QUAD = (size_t)(2 << 20) + (64 << 10) + (4 << 20);
  prep_tables<<<1024, 256, 0, stream>>>(Whh, Wih, WT4h, WT4i);

  if (ws_size >= NEED_QUAD) {
    hipMemsetAsync(flags, 0, 64 * 4 * 2 * 16 * sizeof(unsigned int), stream);
    lstm_quad<<<256, 512, 0, stream>>>(x, WT4h, WT4i, bih, bhh, h0, c0, out,
                                       flags, part);
  } else {
    lstm_fused<<<BATCH, 512, 0, stream>>>(x, WT4h, WT4i, bih, bhh, h0, c0, out);
  }
}